// Round 5
// baseline (40.389 us; speedup 1.0000x reference)
//
#include <hip/hip_runtime.h>
#include <hip/hip_bf16.h>

// RGCN fused: out = relu( [x | agg_r0..agg_r15] @ [w_self | w_rel]^T )
// B=4096, S=10, R=16, F=128, K_total=2176.
// v5: MEASUREMENT ROUND. Byte-identical R2 kernels; rgcn_fused launched TWICE
// (idempotent: output overwritten, not accumulated). dur_v5 - dur_v2 isolates
// the true per-launch cost of rgcn_fused vs fixed harness/graph overhead.

#define BT      16
#define LDA     2184           // bf16 elems per A_t row (2176 + 8 pad)
#define NTHR    512
#define K_STEPS 68             // 2176 / 32
#define W2_UNITS (K_STEPS * 8) // 544 (ks, otile) units
#define W2_BYTES (W2_UNITS * 64 * 16)  // 557,056

typedef __attribute__((ext_vector_type(8))) short short8;  // 8 bf16
typedef __attribute__((ext_vector_type(4))) float f32x4;   // MFMA acc

// fp32 pair -> packed bf16 (RNE) in one instruction
__device__ __forceinline__ unsigned int pk2_rne(float lo, float hi) {
  unsigned int r;
  asm("v_cvt_pk_bf16_f32 %0, %1, %2" : "=v"(r) : "v"(lo), "v"(hi));
  return r;
}

// ---- prep: W (fp32) -> bf16 fragments, layout [ks][ot][lane] 16B per lane ----
__global__ __launch_bounds__(256)
void wprep(const float* __restrict__ w_self, const float* __restrict__ w_rel,
           uint4* __restrict__ w2)
{
  const int u  = blockIdx.x * 4 + (threadIdx.x >> 6);   // 0..543
  const int l  = threadIdx.x & 63;
  const int ln = l & 15, lj = l >> 4;
  const int ks = u >> 3, ot = u & 7;
  const int o  = ot * 16 + ln;
  const int k0 = ks * 32 + lj * 8;
  const float* src;
  if (k0 < 128) src = w_self + o * 128 + k0;
  else {
    const int r = (k0 - 128) >> 7, kc = (k0 - 128) & 127;
    src = w_rel + ((size_t)(r * 128 + o)) * 128 + kc;
  }
  const float4 a = *(const float4*)src;
  const float4 b = *(const float4*)(src + 4);
  uint4 v;
  v.x = pk2_rne(a.x, a.y); v.y = pk2_rne(a.z, a.w);
  v.z = pk2_rne(b.x, b.y); v.w = pk2_rne(b.z, b.w);
  w2[u * 64 + l] = v;
}

template<bool USE_W2>
__global__ __launch_bounds__(NTHR, 2)
void rgcn_fused(const float* __restrict__ emb,
                const float* __restrict__ w_self,
                const float* __restrict__ w_rel,
                const int*   __restrict__ nodes,
                const int*   __restrict__ neighbors,
                const int*   __restrict__ rel_mask,
                const uint4* __restrict__ w2,
                float*       __restrict__ out)
{
  __shared__ alignas(16) char smem[80128];
  unsigned short* A_t = (unsigned short*)smem;                  // [16][2184] bf16
  float (*mscale)[10][16] = (float (*)[10][16])(smem + 69888);  // [16][10][16]

  const int t  = threadIdx.x;
  const int b0 = blockIdx.x * BT;
  const int l  = t & 63;
  const int w  = t >> 6;

  // ---------- A0: rel_mask -> mscale[b][s][r] = m/(count+eps) ----------
  if (t < 256) {
    const int bi = t >> 4, r = t & 15;
    const int* mp = rel_mask + (size_t)(b0 + bi) * 160 + r;
    int mb[10]; int c = 0;
    #pragma unroll
    for (int s = 0; s < 10; ++s) { mb[s] = mp[s * 16]; c += mb[s]; }
    const float inv = 1.0f / ((float)c + 1e-10f);
    #pragma unroll
    for (int s = 0; s < 10; ++s) mscale[bi][s][r] = mb[s] ? inv : 0.0f;
  }
  __syncthreads();

  // ---------- A: build A_t rows (self + 16 masked means), bf16 ----------
  {
    const int bi = t >> 5;          // node slot 0..15
    const int f0 = (t & 31) * 4;    // 4 features per lane
    const int b  = b0 + bi;
    const int node = nodes[b];
    int nb[10];
    #pragma unroll
    for (int s = 0; s < 10; ++s) nb[s] = neighbors[b * 10 + s];
    float4 ne[10];
    #pragma unroll
    for (int s = 0; s < 10; ++s)
      ne[s] = *(const float4*)(emb + (size_t)nb[s] * 128 + f0);
    const float4 x4 = *(const float4*)(emb + (size_t)node * 128 + f0);
    char* arow = (char*)A_t + bi * (LDA * 2);
    uint2 sv; sv.x = pk2_rne(x4.x, x4.y); sv.y = pk2_rne(x4.z, x4.w);
    *(uint2*)(arow + f0 * 2) = sv;                      // self block, k in [0,128)

    #pragma unroll
    for (int rc = 0; rc < 4; ++rc) {                    // 4 relations at a time
      float acc[4][4];
      #pragma unroll
      for (int rr = 0; rr < 4; ++rr) { acc[rr][0]=0.f; acc[rr][1]=0.f; acc[rr][2]=0.f; acc[rr][3]=0.f; }
      #pragma unroll
      for (int s = 0; s < 10; ++s) {
        const float4 ms = *(const float4*)(&mscale[bi][s][rc * 4]);
        const float m[4] = {ms.x, ms.y, ms.z, ms.w};
        const float4 v = ne[s];
        #pragma unroll
        for (int rr = 0; rr < 4; ++rr) {
          acc[rr][0] += m[rr] * v.x;
          acc[rr][1] += m[rr] * v.y;
          acc[rr][2] += m[rr] * v.z;
          acc[rr][3] += m[rr] * v.w;
        }
      }
      #pragma unroll
      for (int rr = 0; rr < 4; ++rr) {
        const int r = rc * 4 + rr;                      // k in [128+128r, 256+128r)
        uint2 v2; v2.x = pk2_rne(acc[rr][0], acc[rr][1]); v2.y = pk2_rne(acc[rr][2], acc[rr][3]);
        *(uint2*)(arow + 256 + r * 256 + f0 * 2) = v2;
      }
    }
  }
  __syncthreads();

  // ---------- B: K-split GEMM. wave w owns k-steps [ksb,kse), all 128 cols ----------
  const int ln = l & 15, lj = l >> 4;
  f32x4 acc[8];
  #pragma unroll
  for (int ot = 0; ot < 8; ++ot) acc[ot] = (f32x4){0.f, 0.f, 0.f, 0.f};
  {
    const int ksb = (w < 4) ? w * 9 : 36 + (w - 4) * 8;
    const int kse = ksb + ((w < 4) ? 9 : 8);
    const char* arow = (const char*)A_t + ln * (LDA * 2);
    for (int ks = ksb; ks < kse; ++ks) {
      const short8 a = *(const short8*)(arow + ks * 64 + lj * 16);
      #pragma unroll
      for (int ot = 0; ot < 8; ++ot) {
        short8 bf;
        if constexpr (USE_W2) {
          union { uint4 u; short8 s; } wv;
          wv.u = w2[(ks * 8 + ot) * 64 + l];
          bf = wv.s;
        } else {
          const int o  = ot * 16 + ln;
          const int k0 = ks * 32 + lj * 8;
          const float* wp;
          if (k0 < 128) wp = w_self + o * 128 + k0;
          else {
            const int r = (k0 - 128) >> 7, kc = (k0 - 128) & 127;
            wp = w_rel + ((size_t)(r * 128 + o)) * 128 + kc;
          }
          const float4 wa = *(const float4*)wp;
          const float4 wb = *(const float4*)(wp + 4);
          union { unsigned int u[4]; short8 s; } cv;
          cv.u[0] = pk2_rne(wa.x, wa.y);
          cv.u[1] = pk2_rne(wa.z, wa.w);
          cv.u[2] = pk2_rne(wb.x, wb.y);
          cv.u[3] = pk2_rne(wb.z, wb.w);
          bf = cv.s;
        }
        acc[ot] = __builtin_amdgcn_mfma_f32_16x16x32_bf16(a, bf, acc[ot], 0, 0, 0);
      }
    }
  }
  __syncthreads();

  // ---------- C: write per-k-group partials (aliases A_t region) ----------
  {
    float* P = (float*)smem;                            // [8][16][132] f32
    #pragma unroll
    for (int ot = 0; ot < 8; ++ot) {
      const int o = ot * 16 + ln;
      #pragma unroll
      for (int j = 0; j < 4; ++j)                       // row = lj*4+j (node), col = o
        P[(w * 16 + lj * 4 + j) * 132 + o] = acc[ot][j];
    }
  }
  __syncthreads();

  // ---------- D: 8-way reduce + relu + store ----------
  {
    const float* P = (const float*)smem;
    const int row = t >> 5, o0 = (t & 31) * 4;
    f32x4 s = {0.f, 0.f, 0.f, 0.f};
    #pragma unroll
    for (int g = 0; g < 8; ++g)
      s += *(const f32x4*)(P + (g * 16 + row) * 132 + o0);
    float4 o4;
    o4.x = fmaxf(s[0], 0.f); o4.y = fmaxf(s[1], 0.f);
    o4.z = fmaxf(s[2], 0.f); o4.w = fmaxf(s[3], 0.f);
    *(float4*)(out + (size_t)(b0 + row) * 128 + o0) = o4;
  }
}

extern "C" void kernel_launch(void* const* d_in, const int* in_sizes, int n_in,
                              void* d_out, int out_size, void* d_ws, size_t ws_size,
                              hipStream_t stream) {
  const float* emb       = (const float*)d_in[0];
  const float* w_self    = (const float*)d_in[1];
  const float* w_rel     = (const float*)d_in[2];
  const int*   nodes     = (const int*)d_in[3];
  const int*   neighbors = (const int*)d_in[4];
  const int*   rel_mask  = (const int*)d_in[5];
  float* out = (float*)d_out;
  (void)in_sizes; (void)n_in; (void)out_size;

  if (d_ws != nullptr && ws_size >= (size_t)W2_BYTES) {
    wprep<<<136, 256, 0, stream>>>(w_self, w_rel, (uint4*)d_ws);
    // Launched TWICE on purpose: second launch overwrites the same output
    // (idempotent, deterministic). dur_v5 - dur_v2 = true cost of one
    // rgcn_fused dispatch, separating kernel time from fixed overhead.
    rgcn_fused<true><<<4096 / BT, NTHR, 0, stream>>>(
        emb, w_self, w_rel, nodes, neighbors, rel_mask, (const uint4*)d_ws, out);
    rgcn_fused<true><<<4096 / BT, NTHR, 0, stream>>>(
        emb, w_self, w_rel, nodes, neighbors, rel_mask, (const uint4*)d_ws, out);
  } else {
    rgcn_fused<false><<<4096 / BT, NTHR, 0, stream>>>(
        emb, w_self, w_rel, nodes, neighbors, rel_mask, nullptr, out);
  }
}

// Round 6
// 20.968 us; speedup vs baseline: 1.9263x; 1.9263x over previous
//
#include <hip/hip_runtime.h>
#include <hip/hip_bf16.h>

// RGCN fused: out = relu( [x | agg_r0..agg_r15] @ [w_self | w_rel]^T )
// B=4096, S=10, R=16, F=128, K_total=2176.
// v6: 256 blocks x 1024 thr (16 waves = 4/SIMD). Raw s_barrier with
// lgkmcnt-only drain keeps W2 prefetch in flight across barriers.
// Phase B: wave = 2 o-tiles x 17 k-steps (1 ds_read feeds 2 MFMAs).
// 4 k-groups reduced via 2 LDS partials + fused add in store pass.

#define BT   16
#define LDA  2184            // bf16 elems per A_t row (2176 + 8 pad)
#define NTHR 1024

typedef __attribute__((ext_vector_type(8))) short short8;  // 8 bf16
typedef __attribute__((ext_vector_type(4))) float f32x4;   // MFMA acc

__device__ __forceinline__ unsigned int pk2_rne(float lo, float hi) {
  unsigned int r;
  asm("v_cvt_pk_bf16_f32 %0, %1, %2" : "=v"(r) : "v"(lo), "v"(hi));
  return r;
}

// Workgroup barrier that drains LDS ops only — leaves global loads (W2
// prefetch, gathers) in flight across the barrier. All pre-barrier LDS
// traffic is covered by lgkmcnt(0); no vmem stores precede any barrier.
__device__ __forceinline__ void barrier_lgkm() {
  __builtin_amdgcn_sched_barrier(0);
  asm volatile("s_waitcnt lgkmcnt(0)" ::: "memory");
  __builtin_amdgcn_s_barrier();
  __builtin_amdgcn_sched_barrier(0);
}

// ---- prep: W (fp32) -> bf16 fragments, layout [ks][ot][lane], 16B/lane ----
__global__ __launch_bounds__(256)
void wprep(const float* __restrict__ w_self, const float* __restrict__ w_rel,
           uint4* __restrict__ w2)
{
  const int u  = blockIdx.x * 4 + (threadIdx.x >> 6);   // 0..543
  const int l  = threadIdx.x & 63;
  const int ln = l & 15, lj = l >> 4;
  const int ks = u >> 3, ot = u & 7;
  const int o  = ot * 16 + ln;
  const int k0 = ks * 32 + lj * 8;
  const float* src;
  if (k0 < 128) src = w_self + o * 128 + k0;
  else {
    const int r = (k0 - 128) >> 7, kc = (k0 - 128) & 127;
    src = w_rel + ((size_t)(r * 128 + o)) * 128 + kc;
  }
  const float4 a = *(const float4*)src;
  const float4 b = *(const float4*)(src + 4);
  uint4 v;
  v.x = pk2_rne(a.x, a.y); v.y = pk2_rne(a.z, a.w);
  v.z = pk2_rne(b.x, b.y); v.w = pk2_rne(b.z, b.w);
  w2[u * 64 + l] = v;
}

__global__ __launch_bounds__(NTHR)
void rgcn_fused(const float* __restrict__ emb,
                const int*   __restrict__ nodes,
                const int*   __restrict__ neighbors,
                const int*   __restrict__ rel_mask,
                const uint4* __restrict__ w2,
                float*       __restrict__ out)
{
  __shared__ alignas(16) char smem[80128];
  unsigned short* A_t = (unsigned short*)smem;                  // [16][2184] bf16
  float* P = (float*)smem;                                      // P0 [16][132]; P1 at +2112 words
  float (*mscale)[10][16] = (float (*)[10][16])(smem + 69888);  // [16][10][16]

  const int t  = threadIdx.x;
  const int l  = t & 63;
  const int w  = t >> 6;           // wave 0..15
  const int b0 = blockIdx.x * BT;

  // phase-B identity: wave = (o-group of 2 tiles) x (k-quarter of 17 ks)
  const int og  = w & 3,  kq = w >> 2;
  const int ot0 = og * 2;
  const int ksq = kq * 17;

  // ---------- index loads (first: gathers depend on them) ----------
  const int bi   = w;              // node slot 0..15 (one per wave)
  const int b    = b0 + bi;
  const int node = nodes[b];
  int nb[10];
  {
    const int2* np = (const int2*)(neighbors + (size_t)b * 10);  // 8B-aligned (40B stride)
    const int2 p0 = np[0], p1 = np[1], p2 = np[2], p3 = np[3], p4 = np[4];
    nb[0]=p0.x; nb[1]=p0.y; nb[2]=p1.x; nb[3]=p1.y; nb[4]=p2.x;
    nb[5]=p2.y; nb[6]=p3.x; nb[7]=p3.y; nb[8]=p4.x; nb[9]=p4.y;
  }

  // ---------- mask loads (waves 0-3 cover 16 nodes x 16 relations) ----------
  int mb[10];
  if (t < 256) {
    const int* mp = rel_mask + (size_t)(b0 + (t >> 4)) * 160 + (t & 15);
    #pragma unroll
    for (int s = 0; s < 10; ++s) mb[s] = mp[s * 16];
  }

  // ---------- W2 prefetch: this wave's first k-step (both o-tiles) ----------
  const uint4* wq = w2 + (size_t)((ksq * 8 + ot0) * 64) + l;
  uint4 c0 = wq[0];                // (ksq, ot0)
  uint4 c1 = wq[64];               // (ksq, ot0+1)
  wq += 512;                       // next k-step

  // ---------- gathers (issued early; consumed in phase A) ----------
  const int f0 = l * 2;            // 2 features per lane
  float2 ne[10];
  #pragma unroll
  for (int s = 0; s < 10; ++s)
    ne[s] = *(const float2*)(emb + (size_t)nb[s] * 128 + f0);
  const float2 x2 = *(const float2*)(emb + (size_t)node * 128 + f0);

  // ---------- mscale[b][s][r] = m/(count+eps) ----------
  if (t < 256) {
    int c = 0;
    #pragma unroll
    for (int s = 0; s < 10; ++s) c += mb[s];
    const float inv = 1.0f / ((float)c + 1e-10f);
    #pragma unroll
    for (int s = 0; s < 10; ++s) mscale[t >> 4][s][t & 15] = mb[s] ? inv : 0.0f;
  }
  barrier_lgkm();

  // ---------- Phase A: wave w builds A_t row w (self + 16 masked means) ----------
  {
    char* arow = (char*)A_t + bi * (LDA * 2);
    *(unsigned int*)(arow + f0 * 2) = pk2_rne(x2.x, x2.y);     // self, k in [0,128)
    float acc[16][2];
    #pragma unroll
    for (int r = 0; r < 16; ++r) { acc[r][0] = 0.f; acc[r][1] = 0.f; }
    #pragma unroll
    for (int s = 0; s < 10; ++s) {
      const float4 m0 = *(const float4*)(&mscale[bi][s][0]);   // uniform -> LDS broadcast
      const float4 m1 = *(const float4*)(&mscale[bi][s][4]);
      const float4 m2 = *(const float4*)(&mscale[bi][s][8]);
      const float4 m3 = *(const float4*)(&mscale[bi][s][12]);
      const float m[16] = {m0.x,m0.y,m0.z,m0.w, m1.x,m1.y,m1.z,m1.w,
                           m2.x,m2.y,m2.z,m2.w, m3.x,m3.y,m3.z,m3.w};
      const float2 v = ne[s];
      #pragma unroll
      for (int r = 0; r < 16; ++r) {
        acc[r][0] += m[r] * v.x;
        acc[r][1] += m[r] * v.y;
      }
    }
    #pragma unroll
    for (int r = 0; r < 16; ++r)                               // rel r: k in [128+128r, ...)
      *(unsigned int*)(arow + 256 + r * 256 + f0 * 2) = pk2_rne(acc[r][0], acc[r][1]);
  }
  barrier_lgkm();

  // ---------- Phase B: 17 k-steps x 2 o-tiles, 1-deep W2 reg pipeline ----------
  const int ln = l & 15, lj = l >> 4;
  f32x4 accA = {0.f,0.f,0.f,0.f}, accB = {0.f,0.f,0.f,0.f};
  {
    const char* ar = (const char*)A_t + ln * (LDA * 2) + lj * 16;
    #pragma unroll
    for (int i = 0; i < 17; ++i) {
      const short8 a = *(const short8*)(ar + (ksq + i) * 64);  // one read, two MFMAs
      const uint4 n0 = wq[0];                                  // prefetch ks+1 (OOB-safe
      const uint4 n1 = wq[64];                                 //  tail reads land in d_ws)
      wq += 512;
      union { uint4 u; short8 s; } u0, u1;
      u0.u = c0; u1.u = c1;
      accA = __builtin_amdgcn_mfma_f32_16x16x32_bf16(a, u0.s, accA, 0, 0, 0);
      accB = __builtin_amdgcn_mfma_f32_16x16x32_bf16(a, u1.s, accB, 0, 0, 0);
      c0 = n0; c1 = n1;
    }
  }
  barrier_lgkm();                  // A_t dead; P0/P1 alias it

  // ---------- Phase C: kq even writes, kq odd accumulates ----------
  {
    float* Pg = P + (kq >> 1) * 2112;          // kq 0,1 -> P0 ; kq 2,3 -> P1
    if ((kq & 1) == 0) {
      #pragma unroll
      for (int j = 0; j < 4; ++j) {
        Pg[(lj*4+j)*132 + ot0*16 + ln]       = accA[j];
        Pg[(lj*4+j)*132 + (ot0+1)*16 + ln]   = accB[j];
      }
    }
    barrier_lgkm();
    if ((kq & 1) == 1) {
      #pragma unroll
      for (int j = 0; j < 4; ++j) {
        Pg[(lj*4+j)*132 + ot0*16 + ln]      += accA[j];
        Pg[(lj*4+j)*132 + (ot0+1)*16 + ln]  += accB[j];
      }
    }
    barrier_lgkm();
  }

  // ---------- Phase D: out = relu(P0 + P1) ----------
  {
    const int row = w;                         // t >> 6
    const int cc  = (t & 63) * 2;
    const float2 pa = *(const float2*)(P + row * 132 + cc);
    const float2 pb = *(const float2*)(P + 2112 + row * 132 + cc);
    float2 o2;
    o2.x = fmaxf(pa.x + pb.x, 0.f);
    o2.y = fmaxf(pa.y + pb.y, 0.f);
    *(float2*)(out + (size_t)(b0 + row) * 128 + cc) = o2;
  }
}

extern "C" void kernel_launch(void* const* d_in, const int* in_sizes, int n_in,
                              void* d_out, int out_size, void* d_ws, size_t ws_size,
                              hipStream_t stream) {
  const float* emb       = (const float*)d_in[0];
  const float* w_self    = (const float*)d_in[1];
  const float* w_rel     = (const float*)d_in[2];
  const int*   nodes     = (const int*)d_in[3];
  const int*   neighbors = (const int*)d_in[4];
  const int*   rel_mask  = (const int*)d_in[5];
  float* out = (float*)d_out;
  (void)in_sizes; (void)n_in; (void)out_size; (void)ws_size;

  wprep<<<136, 256, 0, stream>>>(w_self, w_rel, (uint4*)d_ws);
  rgcn_fused<<<4096 / BT, NTHR, 0, stream>>>(
      emb, nodes, neighbors, rel_mask, (const uint4*)d_ws, out);
}